// Round 1
// baseline (49.248 us; speedup 1.0000x reference)
//
#include <hip/hip_runtime.h>
#include <math.h>

// Ewald real-space potential, N=4096, single system.
// pot = 0.5 * norm_const * sum_{i != j} q_i q_j erf(d_ij * a) / d_ij
// a = 1/(sigma*sqrt(2)) = 1/sqrt(2),  norm_const = 90.0474 / (2*pi)

#define N_ATOMS 4096
#define TILE    256
#define IBLOCKS (N_ATOMS / TILE)        // 16
#define JBLOCKS (N_ATOMS / TILE)        // 16
#define NBLOCKS (IBLOCKS * JBLOCKS)     // 256

__global__ __launch_bounds__(TILE) void ewald_pair_kernel(
    const float* __restrict__ q,
    const float* __restrict__ r,
    float* __restrict__ partial)
{
    __shared__ float sx[TILE], sy[TILE], sz[TILE], sq[TILE];

    const int tid = threadIdx.x;
    const int ib  = blockIdx.x % IBLOCKS;
    const int jb  = blockIdx.x / IBLOCKS;
    const int i   = ib * TILE + tid;
    const int j0  = jb * TILE;

    // Stage the j-tile into LDS (coalesced global reads).
    {
        const int j = j0 + tid;
        sx[tid] = r[3 * j + 0];
        sy[tid] = r[3 * j + 1];
        sz[tid] = r[3 * j + 2];
        sq[tid] = q[j];
    }
    __syncthreads();

    const float xi = r[3 * i + 0];
    const float yi = r[3 * i + 1];
    const float zi = r[3 * i + 2];
    const float qi = q[i];
    const float a  = 0.70710678118654752f;   // 1/sqrt(2)

    float acc = 0.0f;
    #pragma unroll 8
    for (int jj = 0; jj < TILE; ++jj) {
        const int   jg   = j0 + jj;
        const float dx   = xi - sx[jj];       // LDS broadcast reads: conflict-free
        const float dy   = yi - sy[jj];
        const float dz   = zi - sz[jj];
        float d2 = dx * dx + dy * dy + dz * dz;
        // Branch-free diagonal mask (reference's safe-sqrt pattern):
        const float mask = (jg != i) ? 1.0f : 0.0f;
        d2 += (1.0f - mask);                  // d2=1 on diagonal -> no inf/NaN
        const float dinv = rsqrtf(d2);
        const float dist = d2 * dinv;         // ~sqrt(d2)
        acc += mask * sq[jj] * erff(dist * a) * dinv;
    }
    acc *= qi;

    // Deterministic in-block reduction: wave shuffle + LDS across 4 waves.
    for (int off = 32; off > 0; off >>= 1)
        acc += __shfl_down(acc, off, 64);

    __shared__ float wsum[TILE / 64];
    if ((tid & 63) == 0) wsum[tid >> 6] = acc;
    __syncthreads();
    if (tid == 0) {
        float s = 0.0f;
        #pragma unroll
        for (int w = 0; w < TILE / 64; ++w) s += wsum[w];
        partial[blockIdx.x] = s;
    }
}

__global__ __launch_bounds__(NBLOCKS) void ewald_reduce_kernel(
    const float* __restrict__ partial,
    float* __restrict__ out)
{
    const int tid = threadIdx.x;
    float v = partial[tid];                   // NBLOCKS == blockDim.x == 256

    for (int off = 32; off > 0; off >>= 1)
        v += __shfl_down(v, off, 64);

    __shared__ float wsum[NBLOCKS / 64];
    if ((tid & 63) == 0) wsum[tid >> 6] = v;
    __syncthreads();
    if (tid == 0) {
        float s = 0.0f;
        #pragma unroll
        for (int w = 0; w < NBLOCKS / 64; ++w) s += wsum[w];
        const float norm_const = 90.0474f / (2.0f * 3.14159265358979f);
        out[0] = 0.5f * s * norm_const;
    }
}

extern "C" void kernel_launch(void* const* d_in, const int* in_sizes, int n_in,
                              void* d_out, int out_size, void* d_ws, size_t ws_size,
                              hipStream_t stream) {
    const float* q = (const float*)d_in[0];   // [4096]
    const float* r = (const float*)d_in[1];   // [4096,3]
    // d_in[2] = cell (zero -> real-space branch), d_in[3] = batch (all zero): unused.
    float* out     = (float*)d_out;           // [1]
    float* partial = (float*)d_ws;            // NBLOCKS floats of scratch

    ewald_pair_kernel<<<NBLOCKS, TILE, 0, stream>>>(q, r, partial);
    ewald_reduce_kernel<<<1, NBLOCKS, 0, stream>>>(partial, out);
}

// Round 3
// 21.098 us; speedup vs baseline: 2.3343x; 2.3343x over previous
//
#include <hip/hip_runtime.h>
#include <math.h>

// Ewald real-space potential, N=4096, single system.
// pot = 0.5 * norm_const * sum_{i != j} q_i q_j erf(d_ij * a) / d_ij
// a = 1/(sigma*sqrt(2)) = 1/sqrt(2),  norm_const = 90.0474 / (2*pi)

#define N_ATOMS 4096
#define TILE    256                      // threads per block = i-atoms per block
#define IBLOCKS (N_ATOMS / TILE)         // 16
#define JCHUNK  64                       // j-atoms per block
#define NJCH    (N_ATOMS / JCHUNK)       // 64
#define NBLOCKS (IBLOCKS * NJCH)         // 1024 -> 4 blocks/CU, 16 waves/CU

// Fast branchless erf, Abramowitz & Stegun 7.1.26, |err| <= 1.5e-7 for x>=0.
// Uses raw rcp/exp2 hardware transcendentals (1-2 ulp, fine vs 39.36 abs tol).
__device__ __forceinline__ float erf_fast(float x) {
    const float p  = 0.3275911f;
    const float a1 = 0.254829592f, a2 = -0.284496736f, a3 = 1.421413741f,
                a4 = -1.453152027f, a5 = 1.061405429f;
    float t = __builtin_amdgcn_rcpf(fmaf(p, x, 1.0f));       // v_rcp_f32
    float poly = fmaf(fmaf(fmaf(fmaf(a5, t, a4), t, a3), t, a2), t, a1) * t;
    // exp(-x^2) = exp2(-x^2 * log2(e)); v_exp_f32 is base-2
    float e = __builtin_amdgcn_exp2f(-x * x * 1.4426950408889634f);
    return fmaf(-poly, e, 1.0f);
}

__global__ __launch_bounds__(TILE) void ewald_pair_kernel(
    const float* __restrict__ q,
    const float* __restrict__ r,
    float* __restrict__ partial)
{
    __shared__ float sx[JCHUNK], sy[JCHUNK], sz[JCHUNK], sq[JCHUNK];

    const int tid = threadIdx.x;
    const int ib  = blockIdx.x % IBLOCKS;
    const int jb  = blockIdx.x / IBLOCKS;
    const int i   = ib * TILE + tid;
    const int j0  = jb * JCHUNK;

    if (tid < JCHUNK) {
        const int j = j0 + tid;
        sx[tid] = r[3 * j + 0];
        sy[tid] = r[3 * j + 1];
        sz[tid] = r[3 * j + 2];
        sq[tid] = q[j];
    }
    __syncthreads();

    const float xi = r[3 * i + 0];
    const float yi = r[3 * i + 1];
    const float zi = r[3 * i + 2];
    const float qi = q[i];
    const float a  = 0.70710678118654752f;   // 1/sqrt(2)

    float acc = 0.0f;
    #pragma unroll 8
    for (int jj = 0; jj < JCHUNK; ++jj) {
        const int   jg = j0 + jj;
        const float dx = xi - sx[jj];         // LDS broadcast reads: conflict-free
        const float dy = yi - sy[jj];
        const float dz = zi - sz[jj];
        float d2 = fmaf(dx, dx, fmaf(dy, dy, dz * dz));
        const float mask = (jg != i) ? 1.0f : 0.0f;
        d2 += (1.0f - mask);                  // d2=1 on diagonal -> no inf/NaN
        const float dinv = __builtin_amdgcn_rsqf(d2);   // v_rsq_f32
        const float dist = d2 * dinv;         // ~sqrt(d2)
        acc = fmaf(mask * sq[jj], erf_fast(dist * a) * dinv, acc);
    }
    acc *= qi;

    // Deterministic in-block reduction: wave shuffle + LDS across 4 waves.
    for (int off = 32; off > 0; off >>= 1)
        acc += __shfl_down(acc, off, 64);

    __shared__ float wsum[TILE / 64];
    if ((tid & 63) == 0) wsum[tid >> 6] = acc;
    __syncthreads();
    if (tid == 0) {
        float s = 0.0f;
        #pragma unroll
        for (int w = 0; w < TILE / 64; ++w) s += wsum[w];
        partial[blockIdx.x] = s;
    }
}

__global__ __launch_bounds__(256) void ewald_reduce_kernel(
    const float* __restrict__ partial,
    float* __restrict__ out)
{
    const int tid = threadIdx.x;
    float v = 0.0f;
    #pragma unroll
    for (int k = 0; k < NBLOCKS / 256; ++k)
        v += partial[tid + k * 256];

    for (int off = 32; off > 0; off >>= 1)
        v += __shfl_down(v, off, 64);

    __shared__ float wsum[256 / 64];
    if ((tid & 63) == 0) wsum[tid >> 6] = v;
    __syncthreads();
    if (tid == 0) {
        float s = 0.0f;
        #pragma unroll
        for (int w = 0; w < 256 / 64; ++w) s += wsum[w];
        const float norm_const = 90.0474f / (2.0f * 3.14159265358979f);
        out[0] = 0.5f * s * norm_const;
    }
}

extern "C" void kernel_launch(void* const* d_in, const int* in_sizes, int n_in,
                              void* d_out, int out_size, void* d_ws, size_t ws_size,
                              hipStream_t stream) {
    const float* q = (const float*)d_in[0];   // [4096]
    const float* r = (const float*)d_in[1];   // [4096,3]
    // d_in[2] = cell (zero -> real-space branch), d_in[3] = batch (all zero): unused.
    float* out     = (float*)d_out;           // [1]
    float* partial = (float*)d_ws;            // NBLOCKS floats of scratch

    ewald_pair_kernel<<<NBLOCKS, TILE, 0, stream>>>(q, r, partial);
    ewald_reduce_kernel<<<1, 256, 0, stream>>>(partial, out);
}

// Round 4
// 17.089 us; speedup vs baseline: 2.8818x; 1.2346x over previous
//
#include <hip/hip_runtime.h>
#include <math.h>

// Ewald real-space potential, N=4096, single system.
// pot = 0.5 * norm_const * sum_{i != j} q_i q_j erf(d_ij * a) / d_ij
// Symmetric: = norm*0.5*( sum_{diag tiles} + 2 * sum_{lower offdiag tiles} )

#define N_ATOMS 4096
#define T       64                      // tile edge = block size = 1 wave
#define K       (N_ATOMS / T)           // 64 tiles per dim
#define NBLOCKS (K * (K + 1) / 2)       // 2080 lower-triangle tiles

// Fast branchless erf, Abramowitz & Stegun 7.1.26, |err| <= 1.5e-7 for x>=0.
__device__ __forceinline__ float erf_fast(float x) {
    const float p  = 0.3275911f;
    const float a1 = 0.254829592f, a2 = -0.284496736f, a3 = 1.421413741f,
                a4 = -1.453152027f, a5 = 1.061405429f;
    float t = __builtin_amdgcn_rcpf(fmaf(p, x, 1.0f));       // v_rcp_f32
    float poly = fmaf(fmaf(fmaf(fmaf(a5, t, a4), t, a3), t, a2), t, a1) * t;
    float e = __builtin_amdgcn_exp2f(-x * x * 1.4426950408889634f); // v_exp_f32
    return fmaf(-poly, e, 1.0f);
}

__global__ __launch_bounds__(T) void ewald_tri_kernel(
    const float* __restrict__ q,
    const float* __restrict__ r,
    float* __restrict__ partial)
{
    __shared__ float4 s4[T];             // packed (x,y,z,q) j-tile

    // Invert linear block id -> lower-triangle (ib >= jb) tile coords.
    const int t = blockIdx.x;
    int row = (int)((sqrtf(fmaf(8.0f, (float)t, 1.0f)) - 1.0f) * 0.5f);
    while ((row + 1) * (row + 2) / 2 <= t) ++row;   // fp rounding fixups
    while (row * (row + 1) / 2 > t) --row;
    const int ib = row;
    const int jb = t - row * (row + 1) / 2;

    const int lane = threadIdx.x;
    const int i    = ib * T + lane;
    const int j0   = jb * T;

    {   // stage j-tile as float4 (one ds_read_b128 broadcast per pair-iter)
        const int j = j0 + lane;
        s4[lane] = make_float4(r[3 * j + 0], r[3 * j + 1], r[3 * j + 2], q[j]);
    }
    __syncthreads();

    const float xi = r[3 * i + 0];
    const float yi = r[3 * i + 1];
    const float zi = r[3 * i + 2];
    const float qi = q[i];
    const float a  = 0.70710678118654752f;   // 1/sqrt(2)

    float acc = 0.0f;
    if (ib == jb) {
        // Diagonal tile: mask self-pair; near pairs guaranteed -> full path.
        #pragma unroll 8
        for (int jj = 0; jj < T; ++jj) {
            const float4 v = s4[jj];
            const float dx = xi - v.x, dy = yi - v.y, dz = zi - v.z;
            float d2 = fmaf(dx, dx, fmaf(dy, dy, dz * dz));
            const float m = (jj != lane) ? 1.0f : 0.0f;
            d2 += 1.0f - m;                       // d2=1 on diagonal: no NaN
            const float dinv = __builtin_amdgcn_rsqf(d2);
            const float dist = d2 * dinv;
            const float f = erf_fast(dist * a) * dinv;
            acc = fmaf(m * v.w, f, acc);
        }
    } else {
        #pragma unroll 8
        for (int jj = 0; jj < T; ++jj) {
            const float4 v = s4[jj];
            const float dx = xi - v.x, dy = yi - v.y, dz = zi - v.z;
            const float d2 = fmaf(dx, dx, fmaf(dy, dy, dz * dz));
            const float dinv = __builtin_amdgcn_rsqf(d2);
            float f = dinv;                       // d2>31 -> erf==1.0f in fp32
            if (__any(d2 < 31.0f)) {              // wave-uniform branch, ~50% taken
                const float dist = d2 * dinv;
                f = erf_fast(dist * a) * dinv;
            }
            acc = fmaf(v.w, f, acc);
        }
        acc *= 2.0f;                              // off-diag tiles count twice
    }
    acc *= qi;

    // Single-wave block: shuffle reduction only.
    for (int off = 32; off > 0; off >>= 1)
        acc += __shfl_down(acc, off, 64);
    if (lane == 0) partial[blockIdx.x] = acc;
}

__global__ __launch_bounds__(256) void ewald_reduce_kernel(
    const float* __restrict__ partial,
    float* __restrict__ out)
{
    const int tid = threadIdx.x;
    float v = 0.0f;
    #pragma unroll
    for (int k = 0; k < (NBLOCKS + 255) / 256; ++k) {
        const int idx = tid + k * 256;
        if (idx < NBLOCKS) v += partial[idx];     // guard: tail slots are poison
    }

    for (int off = 32; off > 0; off >>= 1)
        v += __shfl_down(v, off, 64);

    __shared__ float wsum[256 / 64];
    if ((tid & 63) == 0) wsum[tid >> 6] = v;
    __syncthreads();
    if (tid == 0) {
        float s = 0.0f;
        #pragma unroll
        for (int w = 0; w < 256 / 64; ++w) s += wsum[w];
        const float norm_const = 90.0474f / (2.0f * 3.14159265358979f);
        out[0] = 0.5f * s * norm_const;
    }
}

extern "C" void kernel_launch(void* const* d_in, const int* in_sizes, int n_in,
                              void* d_out, int out_size, void* d_ws, size_t ws_size,
                              hipStream_t stream) {
    const float* q = (const float*)d_in[0];   // [4096]
    const float* r = (const float*)d_in[1];   // [4096,3]
    // d_in[2] = cell (zero -> real-space branch), d_in[3] = batch (all zero): unused.
    float* out     = (float*)d_out;           // [1]
    float* partial = (float*)d_ws;            // NBLOCKS floats of scratch

    ewald_tri_kernel<<<NBLOCKS, T, 0, stream>>>(q, r, partial);
    ewald_reduce_kernel<<<1, 256, 0, stream>>>(partial, out);
}